// Round 18
// baseline (230.791 us; speedup 1.0000x reference)
//
#include <hip/hip_runtime.h>
#include <hip/hip_bf16.h>
#include <hip/hip_cooperative_groups.h>

namespace cg = cooperative_groups;

#define DIM 768
#define LTOK 1024
#define NBATCH 32
#define KEEP 256

// Correctly-rounded f32 reciprocal robust to compile flags (matches np's
// hoisted `inv = 1/den` reciprocal-multiply chain, proven in R9).
__device__ __forceinline__ float recip_cr_f32(float b) {
    return (float)(1.0 / (double)b);
}

// ONE cooperative kernel, grid 1024 x 256.
// Phase A (all 1024 blocks): entropy of 32 rows/block — 8 rows per wave,
//   4 register-double-buffered row-pairs (R13-proven), LDS term table,
//   R9-verified np binning chain (DO NOT TOUCH):
//     den=(mx-mn)+1e-19f ; inv=RN32(1/den) ; nrm=RN32(s*inv) ;
//     t=RN32(nrm*9) ; q=(int)t  [trunc==floor, 0..9 provable].
// grid.sync (device-scope fence for cross-XCD visibility).
// Phase B (blocks 0..255): R17 fused rank+gather — split-j rank (2 thr/token),
//   keeper copy 2-deep pipelined over 4 waves.  Outputs bit-identical to R17.
__global__ __launch_bounds__(256) void fused_kernel(const float* __restrict__ x,
                                                    double* __restrict__ ent,
                                                    float* __restrict__ out_xm,
                                                    float* __restrict__ out_mask,
                                                    float* __restrict__ out_restore) {
    __shared__ double sbuf[LTOK];        // A: term table (769 used); B: se
    __shared__ int pr[256];
    __shared__ int klist[128];
    __shared__ int kcount;

    int tid = threadIdx.x;

    // ---------- Phase A: entropy ----------
    for (int i = tid; i <= DIM; i += 256) {
        double p = (double)i / 768.0;
        sbuf[i] = p * log(p + 1e-9);
    }
    __syncthreads();

    {
        int wave = blockIdx.x * 4 + (tid >> 6);       // 0..4095
        int lane = tid & 63;
        int g    = lane >> 5;
        int il   = lane & 31;
        int row0 = wave * 8 + g;
        const float* p = x + (size_t)row0 * DIM + il * 4;

        float4 va[6], vb[6];
        #pragma unroll
        for (int j = 0; j < 6; ++j) va[j] = *(const float4*)(p + j * 128);

        #pragma unroll
        for (int i = 0; i < 4; ++i) {
            if (i < 3) {
                const float* pn = p + (size_t)(i + 1) * 2 * DIM;
                #pragma unroll
                for (int j = 0; j < 6; ++j) vb[j] = *(const float4*)(pn + j * 128);
            }

            float mn = va[0].x, mx = va[0].x;
            #pragma unroll
            for (int j = 0; j < 6; ++j) {
                mn = fminf(fminf(fminf(mn, va[j].x), fminf(va[j].y, va[j].z)), va[j].w);
                mx = fmaxf(fmaxf(fmaxf(mx, va[j].x), fmaxf(va[j].y, va[j].z)), va[j].w);
            }
            #pragma unroll
            for (int off = 16; off > 0; off >>= 1) {
                mn = fminf(mn, __shfl_xor(mn, off, 64));
                mx = fmaxf(mx, __shfl_xor(mx, off, 64));
            }

            float den = (mx - mn) + 1e-19f;   // 1e-19 absorbed
            float inv = recip_cr_f32(den);    // RN32(1/den)

            unsigned long long pk = 0ull;     // 10 bins x 6 bits; lane max 24
            #define ACC(v) do { float s_  = (v) - mn;                          \
                                float nr_ = s_ * inv;                          \
                                float t_  = nr_ * 9.0f;                        \
                                unsigned q = (unsigned)t_;                     \
                                pk = (1ull << (6u * q)) + pk; } while (0)
            #pragma unroll
            for (int j = 0; j < 6; ++j) { ACC(va[j].x); ACC(va[j].y); ACC(va[j].z); ACC(va[j].w); }
            #undef ACC

            pk += __shfl_xor(pk, 1, 64);      // 6-bit level, sums <= 48

            unsigned long long lo = 0ull, hi = 0ull;
            #pragma unroll
            for (int b = 0; b < 5; ++b) {
                lo |= ((pk >> (6 * b)) & 63ull) << (12 * b);
                hi |= ((pk >> (6 * (b + 5))) & 63ull) << (12 * b);
            }
            #pragma unroll
            for (int off = 2; off <= 16; off <<= 1) {
                lo += __shfl_xor(lo, off, 64);
                hi += __shfl_xor(hi, off, 64);
            }

            if (il == 0) {
                double t0 = sbuf[(lo      ) & 4095ull];
                double t1 = sbuf[(lo >> 12) & 4095ull];
                double t2 = sbuf[(lo >> 24) & 4095ull];
                double t3 = sbuf[(lo >> 36) & 4095ull];
                double t4 = sbuf[(lo >> 48) & 4095ull];
                double t5 = sbuf[(hi      ) & 4095ull];
                double t6 = sbuf[(hi >> 12) & 4095ull];
                double t7 = sbuf[(hi >> 24) & 4095ull];
                double t8 = sbuf[(hi >> 36) & 4095ull];
                double t9 = sbuf[(hi >> 48) & 4095ull];
                // numpy pairwise order: tree over first 8, then +t8, +t9
                double s = ((t0 + t1) + (t2 + t3)) + ((t4 + t5) + (t6 + t7));
                s += t8;
                s += t9;
                ent[row0 + i * 2] = -s;
            }

            #pragma unroll
            for (int j = 0; j < 6; ++j) va[j] = vb[j];
        }
    }

    // ---------- grid-wide barrier (device-scope visibility) ----------
    __threadfence();
    cg::this_grid().sync();

    if (blockIdx.x >= NBATCH * 8) return;

    // ---------- Phase B: fused rank + gather ----------
    int n = blockIdx.x >> 3;
    int chunk = blockIdx.x & 7;

    if (tid == 0) kcount = 0;
    for (int i = tid; i < LTOK; i += 256)
        sbuf[i] = ent[n * LTOK + i];
    __syncthreads();

    int t    = tid & 127;
    int half = tid >> 7;
    int l    = chunk * 128 + t;
    double e = sbuf[l];
    int j0 = half * 512;
    int partial = 0;
    #pragma unroll 8
    for (int j = j0; j < j0 + 512; ++j) {
        double ej = sbuf[j];
        partial += (int)((ej > e) | ((ej == e) & (j < l)));
    }
    pr[tid] = partial;
    __syncthreads();

    if (tid < 128) {
        int rank = pr[tid] + pr[tid + 128];
        out_restore[n * LTOK + l] = (float)rank;
        out_mask[n * LTOK + l]    = (rank < KEEP) ? 0.0f : 1.0f;
        if (rank < KEEP) {
            int idx = atomicAdd(&kcount, 1);
            klist[idx] = (l << 16) | rank;
        }
    }
    __syncthreads();

    int nk   = kcount;
    int wv   = tid >> 6;
    int lane = tid & 63;
    const float4* xb = (const float4*)(x + (size_t)n * LTOK * DIM);
    float4*       ob = (float4*)(out_xm + (size_t)n * KEEP * DIM);

    int i = wv;
    float4 a0, a1, a2;
    int rkA = 0;
    if (i < nk) {
        int en = klist[i];
        const float4* s = xb + (size_t)(en >> 16) * (DIM / 4);
        rkA = en & 0xFFFF;
        a0 = s[lane]; a1 = s[lane + 64]; a2 = s[lane + 128];
    }
    while (i < nk) {
        int j = i + 4;
        float4 b0, b1, b2;
        int rkB = 0;
        if (j < nk) {
            int en = klist[j];
            const float4* s = xb + (size_t)(en >> 16) * (DIM / 4);
            rkB = en & 0xFFFF;
            b0 = s[lane]; b1 = s[lane + 64]; b2 = s[lane + 128];
        }
        float4* d = ob + (size_t)rkA * (DIM / 4);
        d[lane] = a0; d[lane + 64] = a1; d[lane + 128] = a2;
        a0 = b0; a1 = b1; a2 = b2; rkA = rkB;
        i = j;
    }
}

extern "C" void kernel_launch(void* const* d_in, const int* in_sizes, int n_in,
                              void* d_out, int out_size, void* d_ws, size_t ws_size,
                              hipStream_t stream) {
    const float* x = (const float*)d_in[0];

    // d_out is float32, outputs concatenated flat: x_masked | mask | ids_restore
    float* out = (float*)d_out;
    float* out_xm      = out;                                   // 32*256*768
    float* out_mask    = out + (size_t)NBATCH * KEEP * DIM;     // 32*1024
    float* out_restore = out_mask + (size_t)NBATCH * LTOK;      // 32*1024

    double* ws_ent = (double*)d_ws;                             // 256 KiB

    void* args[] = { (void*)&x, (void*)&ws_ent, (void*)&out_xm,
                     (void*)&out_mask, (void*)&out_restore };
    hipLaunchCooperativeKernel((void*)fused_kernel, dim3(NBATCH * LTOK / 32),
                               dim3(256), args, 0, stream);
}

// Round 19
// 117.381 us; speedup vs baseline: 1.9662x; 1.9662x over previous
//
#include <hip/hip_runtime.h>
#include <hip/hip_bf16.h>

#define DIM 768
#define LTOK 1024
#define NBATCH 32
#define KEEP 256

// Correctly-rounded f32 reciprocal robust to compile flags (matches np's
// hoisted `inv = 1/den` reciprocal-multiply chain, proven in R9).
__device__ __forceinline__ float recip_cr_f32(float b) {
    return (float)(1.0 / (double)b);
}

// ONE regular kernel, grid 1024 x 256, no grid-wide sync.
// Phase A (all blocks): entropy of rows [32b, 32b+32) — R13-proven pipeline,
//   R9-verified np binning chain (DO NOT TOUCH).  ent[] written with
//   agent-scope atomic stores (visible across non-coherent per-XCD L2s).
// Producer handshake: atomicAdd(done[n], 1) with RELEASE, agent scope.
// Phase B (blocks 0..255): spin until done[n]==32 (ACQUIRE, agent scope,
//   s_sleep backoff), then R17's fused rank+gather, bit-identical.
// Deadlock-free: 256 thr / 32 VGPR / ~10 KB LDS -> >=4 blocks/CU -> all 1024
// blocks co-resident; spinners (256) < capacity (1024).
__global__ __launch_bounds__(256) void fused_kernel(const float* __restrict__ x,
                                                    double* __restrict__ ent,
                                                    int* __restrict__ done,
                                                    float* __restrict__ out_xm,
                                                    float* __restrict__ out_mask,
                                                    float* __restrict__ out_restore) {
    __shared__ double sbuf[LTOK];        // A: term table (769 used); B: se
    __shared__ int pr[256];
    __shared__ int klist[128];
    __shared__ int kcount;

    int tid = threadIdx.x;

    // ---------- Phase A: entropy ----------
    for (int i = tid; i <= DIM; i += 256) {
        double p = (double)i / 768.0;
        sbuf[i] = p * log(p + 1e-9);
    }
    __syncthreads();

    {
        int wave = blockIdx.x * 4 + (tid >> 6);       // 0..4095
        int lane = tid & 63;
        int g    = lane >> 5;
        int il   = lane & 31;
        int row0 = wave * 8 + g;
        const float* p = x + (size_t)row0 * DIM + il * 4;

        float4 va[6], vb[6];
        #pragma unroll
        for (int j = 0; j < 6; ++j) va[j] = *(const float4*)(p + j * 128);

        #pragma unroll
        for (int i = 0; i < 4; ++i) {
            if (i < 3) {
                const float* pn = p + (size_t)(i + 1) * 2 * DIM;
                #pragma unroll
                for (int j = 0; j < 6; ++j) vb[j] = *(const float4*)(pn + j * 128);
            }

            float mn = va[0].x, mx = va[0].x;
            #pragma unroll
            for (int j = 0; j < 6; ++j) {
                mn = fminf(fminf(fminf(mn, va[j].x), fminf(va[j].y, va[j].z)), va[j].w);
                mx = fmaxf(fmaxf(fmaxf(mx, va[j].x), fmaxf(va[j].y, va[j].z)), va[j].w);
            }
            #pragma unroll
            for (int off = 16; off > 0; off >>= 1) {
                mn = fminf(mn, __shfl_xor(mn, off, 64));
                mx = fmaxf(mx, __shfl_xor(mx, off, 64));
            }

            float den = (mx - mn) + 1e-19f;   // 1e-19 absorbed
            float inv = recip_cr_f32(den);    // RN32(1/den)

            unsigned long long pk = 0ull;     // 10 bins x 6 bits; lane max 24
            #define ACC(v) do { float s_  = (v) - mn;                          \
                                float nr_ = s_ * inv;                          \
                                float t_  = nr_ * 9.0f;                        \
                                unsigned q = (unsigned)t_;                     \
                                pk = (1ull << (6u * q)) + pk; } while (0)
            #pragma unroll
            for (int j = 0; j < 6; ++j) { ACC(va[j].x); ACC(va[j].y); ACC(va[j].z); ACC(va[j].w); }
            #undef ACC

            pk += __shfl_xor(pk, 1, 64);      // 6-bit level, sums <= 48

            unsigned long long lo = 0ull, hi = 0ull;
            #pragma unroll
            for (int b = 0; b < 5; ++b) {
                lo |= ((pk >> (6 * b)) & 63ull) << (12 * b);
                hi |= ((pk >> (6 * (b + 5))) & 63ull) << (12 * b);
            }
            #pragma unroll
            for (int off = 2; off <= 16; off <<= 1) {
                lo += __shfl_xor(lo, off, 64);
                hi += __shfl_xor(hi, off, 64);
            }

            if (il == 0) {
                double t0 = sbuf[(lo      ) & 4095ull];
                double t1 = sbuf[(lo >> 12) & 4095ull];
                double t2 = sbuf[(lo >> 24) & 4095ull];
                double t3 = sbuf[(lo >> 36) & 4095ull];
                double t4 = sbuf[(lo >> 48) & 4095ull];
                double t5 = sbuf[(hi      ) & 4095ull];
                double t6 = sbuf[(hi >> 12) & 4095ull];
                double t7 = sbuf[(hi >> 24) & 4095ull];
                double t8 = sbuf[(hi >> 36) & 4095ull];
                double t9 = sbuf[(hi >> 48) & 4095ull];
                // numpy pairwise order: tree over first 8, then +t8, +t9
                double s = ((t0 + t1) + (t2 + t3)) + ((t4 + t5) + (t6 + t7));
                s += t8;
                s += t9;
                __hip_atomic_store(&ent[row0 + i * 2], -s,
                                   __ATOMIC_RELAXED, __HIP_MEMORY_SCOPE_AGENT);
            }

            #pragma unroll
            for (int j = 0; j < 6; ++j) va[j] = vb[j];
        }
    }

    // ---------- producer handshake ----------
    __syncthreads();                      // all ent stores of block issued
    if (tid == 0) {
        int nprod = blockIdx.x >> 5;      // batch this block produced
        __hip_atomic_fetch_add(&done[nprod], 1,
                               __ATOMIC_RELEASE, __HIP_MEMORY_SCOPE_AGENT);
    }

    if (blockIdx.x >= NBATCH * 8) return;

    // ---------- Phase B: wait for this batch, then rank + gather ----------
    int n = blockIdx.x >> 3;
    int chunk = blockIdx.x & 7;

    if (tid == 0) {
        kcount = 0;
        while (__hip_atomic_load(&done[n], __ATOMIC_ACQUIRE,
                                 __HIP_MEMORY_SCOPE_AGENT) < 32) {
            __builtin_amdgcn_s_sleep(8);
        }
    }
    __syncthreads();

    for (int i = tid; i < LTOK; i += 256)
        sbuf[i] = __hip_atomic_load(&ent[n * LTOK + i],
                                    __ATOMIC_RELAXED, __HIP_MEMORY_SCOPE_AGENT);
    __syncthreads();

    int t    = tid & 127;
    int half = tid >> 7;
    int l    = chunk * 128 + t;
    double e = sbuf[l];
    int j0 = half * 512;
    int partial = 0;
    #pragma unroll 8
    for (int j = j0; j < j0 + 512; ++j) {
        double ej = sbuf[j];
        partial += (int)((ej > e) | ((ej == e) & (j < l)));
    }
    pr[tid] = partial;
    __syncthreads();

    if (tid < 128) {
        int rank = pr[tid] + pr[tid + 128];
        out_restore[n * LTOK + l] = (float)rank;
        out_mask[n * LTOK + l]    = (rank < KEEP) ? 0.0f : 1.0f;
        if (rank < KEEP) {
            int idx = atomicAdd(&kcount, 1);
            klist[idx] = (l << 16) | rank;
        }
    }
    __syncthreads();

    int nk   = kcount;
    int wv   = tid >> 6;
    int lane = tid & 63;
    const float4* xb = (const float4*)(x + (size_t)n * LTOK * DIM);
    float4*       ob = (float4*)(out_xm + (size_t)n * KEEP * DIM);

    int i = wv;
    float4 a0, a1, a2;
    int rkA = 0;
    if (i < nk) {
        int en = klist[i];
        const float4* s = xb + (size_t)(en >> 16) * (DIM / 4);
        rkA = en & 0xFFFF;
        a0 = s[lane]; a1 = s[lane + 64]; a2 = s[lane + 128];
    }
    while (i < nk) {
        int j = i + 4;
        float4 b0, b1, b2;
        int rkB = 0;
        if (j < nk) {
            int en = klist[j];
            const float4* s = xb + (size_t)(en >> 16) * (DIM / 4);
            rkB = en & 0xFFFF;
            b0 = s[lane]; b1 = s[lane + 64]; b2 = s[lane + 128];
        }
        float4* d = ob + (size_t)rkA * (DIM / 4);
        d[lane] = a0; d[lane + 64] = a1; d[lane + 128] = a2;
        a0 = b0; a1 = b1; a2 = b2; rkA = rkB;
        i = j;
    }
}

extern "C" void kernel_launch(void* const* d_in, const int* in_sizes, int n_in,
                              void* d_out, int out_size, void* d_ws, size_t ws_size,
                              hipStream_t stream) {
    const float* x = (const float*)d_in[0];

    // d_out is float32, outputs concatenated flat: x_masked | mask | ids_restore
    float* out = (float*)d_out;
    float* out_xm      = out;                                   // 32*256*768
    float* out_mask    = out + (size_t)NBATCH * KEEP * DIM;     // 32*1024
    float* out_restore = out_mask + (size_t)NBATCH * LTOK;      // 32*1024

    double* ws_ent  = (double*)d_ws;                            // 256 KiB
    int*    ws_done = (int*)((char*)d_ws + (size_t)NBATCH * LTOK * sizeof(double));

    // reset per-batch counters (async memset node -> graph-capturable,
    // deterministic across replays)
    hipMemsetAsync(ws_done, 0, NBATCH * sizeof(int), stream);
    fused_kernel<<<dim3(NBATCH * LTOK / 32), 256, 0, stream>>>(
        x, ws_ent, ws_done, out_xm, out_mask, out_restore);
}

// Round 20
// 39.159 us; speedup vs baseline: 5.8938x; 2.9976x over previous
//
#include <hip/hip_runtime.h>
#include <hip/hip_bf16.h>

#define DIM 768
#define LTOK 1024
#define NBATCH 32
#define KEEP 256

// Correctly-rounded f32 reciprocal robust to compile flags (matches np's
// hoisted `inv = 1/den` reciprocal-multiply chain, proven in R9).
__device__ __forceinline__ float recip_cr_f32(float b) {
    return (float)(1.0 / (double)b);
}

// 8 rows per wave: 4 row-pairs, register-double-buffered (R13-proven).
// Term table built ONCE per block in LDS (same f64 expression -> bit-identical).
// R9-verified np binning chain (DO NOT TOUCH):
//   den = (mx-mn)+1e-19f ; inv = RN32(1/den) ; nrm = RN32(s*inv) ;
//   t = RN32(nrm*9) ; q = (int)t  [trunc==floor, q in 0..9 provable].
__global__ __launch_bounds__(256) void ent_kernel(const float* __restrict__ x,
                                                  double* __restrict__ ent) {
    __shared__ double sterm[DIM + 1];
    for (int i = threadIdx.x; i <= DIM; i += 256) {
        double p = (double)i / 768.0;
        sterm[i] = p * log(p + 1e-9);
    }
    __syncthreads();

    int wave = blockIdx.x * 4 + (threadIdx.x >> 6);   // 0..4095
    int lane = threadIdx.x & 63;
    int g    = lane >> 5;
    int il   = lane & 31;
    int row0 = wave * 8 + g;
    const float* p = x + (size_t)row0 * DIM + il * 4;

    float4 va[6], vb[6];
    #pragma unroll
    for (int j = 0; j < 6; ++j) va[j] = *(const float4*)(p + j * 128);

    #pragma unroll
    for (int i = 0; i < 4; ++i) {
        if (i < 3) {
            const float* pn = p + (size_t)(i + 1) * 2 * DIM;
            #pragma unroll
            for (int j = 0; j < 6; ++j) vb[j] = *(const float4*)(pn + j * 128);
        }

        float mn = va[0].x, mx = va[0].x;
        #pragma unroll
        for (int j = 0; j < 6; ++j) {
            mn = fminf(fminf(fminf(mn, va[j].x), fminf(va[j].y, va[j].z)), va[j].w);
            mx = fmaxf(fmaxf(fmaxf(mx, va[j].x), fmaxf(va[j].y, va[j].z)), va[j].w);
        }
        #pragma unroll
        for (int off = 16; off > 0; off >>= 1) {
            mn = fminf(mn, __shfl_xor(mn, off, 64));
            mx = fmaxf(mx, __shfl_xor(mx, off, 64));
        }

        float den = (mx - mn) + 1e-19f;   // 1e-19 absorbed
        float inv = recip_cr_f32(den);    // RN32(1/den)

        unsigned long long pk = 0ull;     // 10 bins x 6 bits; lane max 24
        #define ACC(v) do { float s_  = (v) - mn;                            \
                            float nr_ = s_ * inv;    /* RN32, lone mul */    \
                            float t_  = nr_ * 9.0f;  /* RN32, lone mul */    \
                            unsigned q = (unsigned)t_; /* trunc==floor */    \
                            pk = (1ull << (6u * q)) + pk; } while (0)
        #pragma unroll
        for (int j = 0; j < 6; ++j) { ACC(va[j].x); ACC(va[j].y); ACC(va[j].z); ACC(va[j].w); }
        #undef ACC

        pk += __shfl_xor(pk, 1, 64);      // 6-bit level, sums <= 48

        unsigned long long lo = 0ull, hi = 0ull;
        #pragma unroll
        for (int b = 0; b < 5; ++b) {
            lo |= ((pk >> (6 * b)) & 63ull) << (12 * b);
            hi |= ((pk >> (6 * (b + 5))) & 63ull) << (12 * b);
        }
        #pragma unroll
        for (int off = 2; off <= 16; off <<= 1) {
            lo += __shfl_xor(lo, off, 64);
            hi += __shfl_xor(hi, off, 64);
        }

        if (il == 0) {
            double t0 = sterm[(lo      ) & 4095ull];
            double t1 = sterm[(lo >> 12) & 4095ull];
            double t2 = sterm[(lo >> 24) & 4095ull];
            double t3 = sterm[(lo >> 36) & 4095ull];
            double t4 = sterm[(lo >> 48) & 4095ull];
            double t5 = sterm[(hi      ) & 4095ull];
            double t6 = sterm[(hi >> 12) & 4095ull];
            double t7 = sterm[(hi >> 24) & 4095ull];
            double t8 = sterm[(hi >> 36) & 4095ull];
            double t9 = sterm[(hi >> 48) & 4095ull];
            // numpy pairwise order: tree over first 8, then +t8, +t9
            double s = ((t0 + t1) + (t2 + t3)) + ((t4 + t5) + (t6 + t7));
            s += t8;
            s += t9;
            ent[row0 + i * 2] = -s;
        }

        #pragma unroll
        for (int j = 0; j < 6; ++j) va[j] = vb[j];
    }
}

// Fused rank + gather (R17 structure, widened).  512 threads/block, grid (32,8).
// Rank: 4 threads per token split the 1024-iter loop into 256-iter quarters,
// partials combined via LDS.  Gather: keepers copied by 8 waves, 2-deep
// software pipeline.  Unique (n,rank) destinations => deterministic.
__global__ __launch_bounds__(512) void rankgather_kernel(const double* __restrict__ ent,
                                                         const float* __restrict__ x,
                                                         float* __restrict__ out_xm,
                                                         float* __restrict__ out_mask,
                                                         float* __restrict__ out_restore) {
    __shared__ double se[LTOK];
    __shared__ int pr[512];
    __shared__ int klist[128];
    __shared__ int kcount;
    int n = blockIdx.x;      // 0..31
    int chunk = blockIdx.y;  // 0..7
    int tid = threadIdx.x;

    if (tid == 0) kcount = 0;
    for (int i = tid; i < LTOK; i += 512)
        se[i] = ent[n * LTOK + i];
    __syncthreads();

    int t    = tid & 127;            // token within chunk
    int quar = tid >> 7;             // j-range quarter (0..3)
    int l    = chunk * 128 + t;
    double e = se[l];
    int j0 = quar * 256;
    int partial = 0;
    #pragma unroll 8
    for (int j = j0; j < j0 + 256; ++j) {
        double ej = se[j];
        partial += (int)((ej > e) | ((ej == e) & (j < l)));
    }
    pr[tid] = partial;
    __syncthreads();

    if (tid < 128) {
        int rank = pr[tid] + pr[tid + 128] + pr[tid + 256] + pr[tid + 384];
        out_restore[n * LTOK + l] = (float)rank;
        out_mask[n * LTOK + l]    = (rank < KEEP) ? 0.0f : 1.0f;
        if (rank < KEEP) {
            int idx = atomicAdd(&kcount, 1);
            klist[idx] = (l << 16) | rank;
        }
    }
    __syncthreads();

    // gather: 8 waves, wave wv takes klist[wv], klist[wv+8], ...
    int nk   = kcount;
    int wv   = tid >> 6;
    int lane = tid & 63;
    const float4* xb = (const float4*)(x + (size_t)n * LTOK * DIM);
    float4*       ob = (float4*)(out_xm + (size_t)n * KEEP * DIM);

    int i = wv;
    float4 a0, a1, a2;
    int rkA = 0;
    if (i < nk) {
        int en = klist[i];
        const float4* s = xb + (size_t)(en >> 16) * (DIM / 4);
        rkA = en & 0xFFFF;
        a0 = s[lane]; a1 = s[lane + 64]; a2 = s[lane + 128];
    }
    while (i < nk) {
        int j = i + 8;
        float4 b0, b1, b2;
        int rkB = 0;
        if (j < nk) {
            int en = klist[j];
            const float4* s = xb + (size_t)(en >> 16) * (DIM / 4);
            rkB = en & 0xFFFF;
            b0 = s[lane]; b1 = s[lane + 64]; b2 = s[lane + 128];
        }
        float4* d = ob + (size_t)rkA * (DIM / 4);
        d[lane] = a0; d[lane + 64] = a1; d[lane + 128] = a2;
        a0 = b0; a1 = b1; a2 = b2; rkA = rkB;
        i = j;
    }
}

extern "C" void kernel_launch(void* const* d_in, const int* in_sizes, int n_in,
                              void* d_out, int out_size, void* d_ws, size_t ws_size,
                              hipStream_t stream) {
    const float* x = (const float*)d_in[0];

    // d_out is float32, outputs concatenated flat: x_masked | mask | ids_restore
    float* out = (float*)d_out;
    float* out_xm      = out;                                   // 32*256*768
    float* out_mask    = out + (size_t)NBATCH * KEEP * DIM;     // 32*1024
    float* out_restore = out_mask + (size_t)NBATCH * LTOK;      // 32*1024

    double* ws_ent = (double*)d_ws;                             // 256 KiB

    ent_kernel<<<dim3(NBATCH * LTOK / 32), 256, 0, stream>>>(x, ws_ent);
    rankgather_kernel<<<dim3(NBATCH, 8), 512, 0, stream>>>(ws_ent, x, out_xm, out_mask, out_restore);
}

// Round 21
// 38.401 us; speedup vs baseline: 6.0101x; 1.0197x over previous
//
#include <hip/hip_runtime.h>
#include <hip/hip_bf16.h>

#define DIM 768
#define LTOK 1024
#define NBATCH 32
#define KEEP 256

// Correctly-rounded f32 reciprocal robust to compile flags (matches np's
// hoisted `inv = 1/den` reciprocal-multiply chain, proven in R9).
__device__ __forceinline__ float recip_cr_f32(float b) {
    return (float)(1.0 / (double)b);
}

__device__ __forceinline__ float min4(float4 v) {
    return fminf(fminf(v.x, v.y), fminf(v.z, v.w));
}
__device__ __forceinline__ float max4(float4 v) {
    return fmaxf(fmaxf(v.x, v.y), fmaxf(v.z, v.w));
}

// 8 rows per wave: 4 row-pairs, register-double-buffered (R13-proven).
// First pair's loads are issued BEFORE the LDS term-table build so the
// global traffic flies under the per-block log computation.
// R9-verified np binning chain (DO NOT TOUCH):
//   den = (mx-mn)+1e-19f ; inv = RN32(1/den) ; nrm = RN32(s*inv) ;
//   t = RN32(nrm*9) ; q = (int)t  [trunc==floor, q in 0..9 provable].
__global__ __launch_bounds__(256) void ent_kernel(const float* __restrict__ x,
                                                  double* __restrict__ ent) {
    __shared__ double sterm[DIM + 1];

    int wave = blockIdx.x * 4 + (threadIdx.x >> 6);   // 0..4095
    int lane = threadIdx.x & 63;
    int g    = lane >> 5;
    int il   = lane & 31;
    int row0 = wave * 8 + g;
    const float* p = x + (size_t)row0 * DIM + il * 4;

    // issue first pair's loads BEFORE the table build (hide logs under HBM)
    float4 va[6], vb[6];
    #pragma unroll
    for (int j = 0; j < 6; ++j) va[j] = *(const float4*)(p + j * 128);

    // term[c] = (c/768)*log(c/768 + 1e-9) — same expression, bit-identical
    for (int i = threadIdx.x; i <= DIM; i += 256) {
        double pd = (double)i / 768.0;
        sterm[i] = pd * log(pd + 1e-9);
    }
    __syncthreads();

    #pragma unroll
    for (int i = 0; i < 4; ++i) {
        if (i < 3) {
            const float* pn = p + (size_t)(i + 1) * 2 * DIM;
            #pragma unroll
            for (int j = 0; j < 6; ++j) vb[j] = *(const float4*)(pn + j * 128);
        }

        // tree min/max: depth ~6 instead of ~24
        float mn = fminf(fminf(min4(va[0]), min4(va[1])),
                         fminf(fminf(min4(va[2]), min4(va[3])),
                               fminf(min4(va[4]), min4(va[5]))));
        float mx = fmaxf(fmaxf(max4(va[0]), max4(va[1])),
                         fmaxf(fmaxf(max4(va[2]), max4(va[3])),
                               fmaxf(max4(va[4]), max4(va[5]))));
        #pragma unroll
        for (int off = 16; off > 0; off >>= 1) {
            mn = fminf(mn, __shfl_xor(mn, off, 64));
            mx = fmaxf(mx, __shfl_xor(mx, off, 64));
        }

        float den = (mx - mn) + 1e-19f;   // 1e-19 absorbed
        float inv = recip_cr_f32(den);    // RN32(1/den)

        unsigned long long pk = 0ull;     // 10 bins x 6 bits; lane max 24
        #define ACC(v) do { float s_  = (v) - mn;                            \
                            float nr_ = s_ * inv;    /* RN32, lone mul */    \
                            float t_  = nr_ * 9.0f;  /* RN32, lone mul */    \
                            unsigned q = (unsigned)t_; /* trunc==floor */    \
                            pk = (1ull << (6u * q)) + pk; } while (0)
        #pragma unroll
        for (int j = 0; j < 6; ++j) { ACC(va[j].x); ACC(va[j].y); ACC(va[j].z); ACC(va[j].w); }
        #undef ACC

        pk += __shfl_xor(pk, 1, 64);      // 6-bit level, sums <= 48

        unsigned long long lo = 0ull, hi = 0ull;
        #pragma unroll
        for (int b = 0; b < 5; ++b) {
            lo |= ((pk >> (6 * b)) & 63ull) << (12 * b);
            hi |= ((pk >> (6 * (b + 5))) & 63ull) << (12 * b);
        }
        #pragma unroll
        for (int off = 2; off <= 16; off <<= 1) {
            lo += __shfl_xor(lo, off, 64);
            hi += __shfl_xor(hi, off, 64);
        }

        if (il == 0) {
            double t0 = sterm[(lo      ) & 4095ull];
            double t1 = sterm[(lo >> 12) & 4095ull];
            double t2 = sterm[(lo >> 24) & 4095ull];
            double t3 = sterm[(lo >> 36) & 4095ull];
            double t4 = sterm[(lo >> 48) & 4095ull];
            double t5 = sterm[(hi      ) & 4095ull];
            double t6 = sterm[(hi >> 12) & 4095ull];
            double t7 = sterm[(hi >> 24) & 4095ull];
            double t8 = sterm[(hi >> 36) & 4095ull];
            double t9 = sterm[(hi >> 48) & 4095ull];
            // numpy pairwise order: tree over first 8, then +t8, +t9
            double s = ((t0 + t1) + (t2 + t3)) + ((t4 + t5) + (t6 + t7));
            s += t8;
            s += t9;
            ent[row0 + i * 2] = -s;
        }

        #pragma unroll
        for (int j = 0; j < 6; ++j) va[j] = vb[j];
    }
}

// Fused rank + gather (R17/R20 structure).  512 threads/block, grid (32,8).
// Rank: 4 threads per token, 256-iter quarters, double2 LDS reads (half the
// ds_read issue count; broadcast reads, conflict-free).
// Gather: keepers copied by 8 waves, 2-deep software pipeline.
__global__ __launch_bounds__(512) void rankgather_kernel(const double* __restrict__ ent,
                                                         const float* __restrict__ x,
                                                         float* __restrict__ out_xm,
                                                         float* __restrict__ out_mask,
                                                         float* __restrict__ out_restore) {
    __shared__ alignas(16) double se[LTOK];
    __shared__ int pr[512];
    __shared__ int klist[128];
    __shared__ int kcount;
    int n = blockIdx.x;      // 0..31
    int chunk = blockIdx.y;  // 0..7
    int tid = threadIdx.x;

    if (tid == 0) kcount = 0;
    for (int i = tid; i < LTOK; i += 512)
        se[i] = ent[n * LTOK + i];
    __syncthreads();

    int t    = tid & 127;            // token within chunk
    int quar = tid >> 7;             // j-range quarter (0..3)
    int l    = chunk * 128 + t;
    double e = se[l];
    const double2* se2 = (const double2*)se;
    int jj0 = quar * 128;            // double2 index; j = 2*jj
    int partial = 0;
    #pragma unroll 8
    for (int jj = jj0; jj < jj0 + 128; ++jj) {
        double2 ej = se2[jj];
        int j0 = jj * 2;
        partial += (int)((ej.x > e) | ((ej.x == e) & (j0     < l)));
        partial += (int)((ej.y > e) | ((ej.y == e) & (j0 + 1 < l)));
    }
    pr[tid] = partial;
    __syncthreads();

    if (tid < 128) {
        int rank = pr[tid] + pr[tid + 128] + pr[tid + 256] + pr[tid + 384];
        out_restore[n * LTOK + l] = (float)rank;
        out_mask[n * LTOK + l]    = (rank < KEEP) ? 0.0f : 1.0f;
        if (rank < KEEP) {
            int idx = atomicAdd(&kcount, 1);
            klist[idx] = (l << 16) | rank;
        }
    }
    __syncthreads();

    // gather: 8 waves, wave wv takes klist[wv], klist[wv+8], ...
    int nk   = kcount;
    int wv   = tid >> 6;
    int lane = tid & 63;
    const float4* xb = (const float4*)(x + (size_t)n * LTOK * DIM);
    float4*       ob = (float4*)(out_xm + (size_t)n * KEEP * DIM);

    int i = wv;
    float4 a0, a1, a2;
    int rkA = 0;
    if (i < nk) {
        int en = klist[i];
        const float4* s = xb + (size_t)(en >> 16) * (DIM / 4);
        rkA = en & 0xFFFF;
        a0 = s[lane]; a1 = s[lane + 64]; a2 = s[lane + 128];
    }
    while (i < nk) {
        int j = i + 8;
        float4 b0, b1, b2;
        int rkB = 0;
        if (j < nk) {
            int en = klist[j];
            const float4* s = xb + (size_t)(en >> 16) * (DIM / 4);
            rkB = en & 0xFFFF;
            b0 = s[lane]; b1 = s[lane + 64]; b2 = s[lane + 128];
        }
        float4* d = ob + (size_t)rkA * (DIM / 4);
        d[lane] = a0; d[lane + 64] = a1; d[lane + 128] = a2;
        a0 = b0; a1 = b1; a2 = b2; rkA = rkB;
        i = j;
    }
}

extern "C" void kernel_launch(void* const* d_in, const int* in_sizes, int n_in,
                              void* d_out, int out_size, void* d_ws, size_t ws_size,
                              hipStream_t stream) {
    const float* x = (const float*)d_in[0];

    // d_out is float32, outputs concatenated flat: x_masked | mask | ids_restore
    float* out = (float*)d_out;
    float* out_xm      = out;                                   // 32*256*768
    float* out_mask    = out + (size_t)NBATCH * KEEP * DIM;     // 32*1024
    float* out_restore = out_mask + (size_t)NBATCH * LTOK;      // 32*1024

    double* ws_ent = (double*)d_ws;                             // 256 KiB

    ent_kernel<<<dim3(NBATCH * LTOK / 32), 256, 0, stream>>>(x, ws_ent);
    rankgather_kernel<<<dim3(NBATCH, 8), 512, 0, stream>>>(ws_ent, x, out_xm, out_mask, out_restore);
}